// Round 1
// 649.739 us; speedup vs baseline: 1.0006x; 1.0006x over previous
//
#include <hip/hip_runtime.h>
#include <math.h>

#define BLOCK 256
#define GROUPS_PER_BLOCK (BLOCK / 32)   // 8 groups (samples quads) per block

// One 32-lane group processes FOUR consecutive samples per iteration:
// lane l loads f[s*128 + l*4 .. +3] as float4 for s = 4q..4q+3.
// 4 independent 1KB wave-loads in flight (4x the MLP of v1), labels via one
// int4 broadcast load, and a packed 12-shfl reduction for all 4 samples.
__global__ __launch_bounds__(BLOCK, 4) void center_loss_main(
    const float* __restrict__ f,
    const float* __restrict__ center,
    const int* __restrict__ t,
    float* __restrict__ ws,   // ws[0]=sum0 ws[1]=sum1 ws[2]=cnt0 ws[3]=cnt1
    int N)
{
    const int lane = threadIdx.x & 31;
    const int grp  = threadIdx.x >> 5;
    const int groups_total = gridDim.x * GROUPS_PER_BLOCK;
    const int g0 = blockIdx.x * GROUPS_PER_BLOCK + grp;
    const int NQ = N >> 2;               // 250000 sample-quads (N % 4 == 0)

    const float4* __restrict__ f4 = (const float4*)f;
    const int4*   __restrict__ t4 = (const int4*)t;
    const float4* __restrict__ c4 = (const float4*)center;
    const float4 c0 = c4[lane];          // center[0][lane*4..+3]
    const float4 c1 = c4[32 + lane];     // center[1][...]

    float sum0 = 0.f, sum1 = 0.f, cnt0 = 0.f, cnt1 = 0.f;

    for (int q = g0; q < NQ; q += groups_total) {
        // ---- issue all 5 loads up front (independent addresses) ----
        const int4 tq = t4[q];                    // labels for samples 4q..4q+3
        const int base = q * 128 + lane;          // float4 index; max ~32M < 2^31
        const float4 fv0 = f4[base];
        const float4 fv1 = f4[base + 32];
        const float4 fv2 = f4[base + 64];
        const float4 fv3 = f4[base + 96];

        // ---- per-sample squared-distance partials (4 independent) ----
        const float4 ca0 = (tq.x == 0) ? c0 : c1;
        const float4 ca1 = (tq.y == 0) ? c0 : c1;
        const float4 ca2 = (tq.z == 0) ? c0 : c1;
        const float4 ca3 = (tq.w == 0) ? c0 : c1;

        float dx, dy, dz, dw;
        dx = fv0.x - ca0.x; dy = fv0.y - ca0.y; dz = fv0.z - ca0.z; dw = fv0.w - ca0.w;
        float ss0 = dx*dx + dy*dy + dz*dz + dw*dw;
        dx = fv1.x - ca1.x; dy = fv1.y - ca1.y; dz = fv1.z - ca1.z; dw = fv1.w - ca1.w;
        float ss1 = dx*dx + dy*dy + dz*dz + dw*dw;
        dx = fv2.x - ca2.x; dy = fv2.y - ca2.y; dz = fv2.z - ca2.z; dw = fv2.w - ca2.w;
        float ss2 = dx*dx + dy*dy + dz*dz + dw*dw;
        dx = fv3.x - ca3.x; dy = fv3.y - ca3.y; dz = fv3.z - ca3.z; dw = fv3.w - ca3.w;
        float ss3 = dx*dx + dy*dy + dz*dz + dw*dw;

        // ---- packed reduction: 12 shfls for 4 samples (vs 20) ----
        ss0 += __shfl_xor(ss0, 16, 32);
        ss1 += __shfl_xor(ss1, 16, 32);
        ss2 += __shfl_xor(ss2, 16, 32);
        ss3 += __shfl_xor(ss3, 16, 32);
        const bool hi = (lane & 16) != 0;
        float a = hi ? ss1 : ss0;   // lanes 0-15 reduce ss0, 16-31 reduce ss1
        float b = hi ? ss3 : ss2;
        a += __shfl_xor(a, 8, 32);  b += __shfl_xor(b, 8, 32);
        a += __shfl_xor(a, 4, 32);  b += __shfl_xor(b, 4, 32);
        a += __shfl_xor(a, 2, 32);  b += __shfl_xor(b, 2, 32);
        a += __shfl_xor(a, 1, 32);  b += __shfl_xor(b, 1, 32);

        // lane 0 holds full sums of (ss0, ss2); lane 16 holds (ss1, ss3)
        if ((lane & 15) == 0) {
            const int clsA = hi ? tq.y : tq.x;
            const int clsB = hi ? tq.w : tq.z;
            const float da = sqrtf(a);
            const float db = sqrtf(b);
            if (clsA == 0) { sum0 += da; cnt0 += 1.f; } else { sum1 += da; cnt1 += 1.f; }
            if (clsB == 0) { sum0 += db; cnt0 += 1.f; } else { sum1 += db; cnt1 += 1.f; }
        }
    }

    // fold lane16 partials into lane0 of each group (once per kernel)
    sum0 += __shfl_xor(sum0, 16, 32);
    sum1 += __shfl_xor(sum1, 16, 32);
    cnt0 += __shfl_xor(cnt0, 16, 32);
    cnt1 += __shfl_xor(cnt1, 16, 32);

    // block reduction: 8 group leads -> LDS -> 4 atomics per block
    __shared__ float ls[4][GROUPS_PER_BLOCK];
    if (lane == 0) {
        ls[0][grp] = sum0;
        ls[1][grp] = sum1;
        ls[2][grp] = cnt0;
        ls[3][grp] = cnt1;
    }
    __syncthreads();
    if (threadIdx.x < 4) {
        float v = 0.f;
#pragma unroll
        for (int i = 0; i < GROUPS_PER_BLOCK; ++i) v += ls[threadIdx.x][i];
        atomicAdd(&ws[threadIdx.x], v);
    }
}

__global__ void center_loss_final(const float* __restrict__ ws,
                                  float* __restrict__ out)
{
    const float s0 = ws[0], s1 = ws[1], c0 = ws[2], c1 = ws[3];
    float r = 0.f;
    if (c0 > 0.f) r += s0 / c0;
    if (c1 > 0.f) r += s1 / c1;
    out[0] = r;
}

extern "C" void kernel_launch(void* const* d_in, const int* in_sizes, int n_in,
                              void* d_out, int out_size, void* d_ws, size_t ws_size,
                              hipStream_t stream)
{
    const float* f      = (const float*)d_in[0];
    const float* center = (const float*)d_in[1];
    const int*   t      = (const int*)d_in[2];   // integer input -> int32 per harness
    float* out = (float*)d_out;
    float* ws  = (float*)d_ws;

    const int N = in_sizes[0] / 128;   // 1,000,000

    // ws is poisoned to 0xAA before every timed call — zero the accumulators.
    hipMemsetAsync(ws, 0, 4 * sizeof(float), stream);

    const int grid = 2048;  // 8 blocks/CU, grid-stride over 250k sample-quads
    center_loss_main<<<grid, BLOCK, 0, stream>>>(f, center, t, ws, N);
    center_loss_final<<<1, 1, 0, stream>>>(ws, out);
}